// Round 7
// baseline (9363.263 us; speedup 1.0000x reference)
//
#include <hip/hip_runtime.h>

// ---------------------------------------------------------------------------
// BiGRU encoder, MI355X. Round 7 = round 6 (proven) + XCD-local sync mode.
// Workers bid%8 in {0,1} -> each direction's 32 blocks on one XCD (verified
// at runtime via XCC_ID rendezvous; any doubt -> exact r6 L3 protocol).
// Local mode: plain write-back h stores (dirty in shared XCD L2), vmcnt drain,
// plain flag + sc0 poll (L2-served). Escape hatch: agent/L3 flag copy.
//
// ws layout:
//   Xb   [T][B][F] bf16      33,554,432 B
//   Hf   [T][B][F] bf16      33,554,432 B
//   Hb   [T][B][F] bf16      33,554,432 B
//   Wb   [2][2][1536][512]    6,291,456 B   (dir, src{0=Whh,1=Wih})
//   meta 192 int: pflags[2][32] @0, wtflags[2][32] @64, xcc[2][32] @128
// ---------------------------------------------------------------------------

#define TT 2048
#define BB 16
#define FF 512
#define LL 10
#define RD 4
#define NW 32
#define NTHR 128

typedef __attribute__((ext_vector_type(8))) short short8;
typedef __attribute__((ext_vector_type(4))) int   int4v;
typedef __attribute__((ext_vector_type(4))) float f32x4;

// D = A*B + C, B operand pinned to AGPR (weights live there loop-invariantly).
#define MFMA_AB(acc, a, b) \
  asm("v_mfma_f32_16x16x32_bf16 %0, %1, %2, %0" : "+v"(acc) : "v"(a), "a"(b))

__device__ __forceinline__ unsigned short f2bf(float f) {
  union { float f; unsigned int u; } v; v.f = f;
  unsigned int u = v.u;
  return (unsigned short)((u + 0x7fffu + ((u >> 16) & 1u)) >> 16);
}
__device__ __forceinline__ float bf2f(unsigned short h) {
  union { unsigned int u; float f; } v; v.u = ((unsigned int)h) << 16;
  return v.f;
}

__global__ void prep_x(const float* __restrict__ x, unsigned short* __restrict__ Xb) {
  int i = blockIdx.x * blockDim.x + threadIdx.x;
  int f = i & (FF - 1);
  int b = (i >> 9) & (BB - 1);
  int t = i >> 13;
  Xb[i] = f2bf(x[(size_t)b * (TT * 1025) + t * 1025 + f]);
}

__global__ void prep_w(const float* __restrict__ a, const float* __restrict__ b,
                       const float* __restrict__ c, const float* __restrict__ d,
                       unsigned short* __restrict__ Wb) {
  const int M = 1536 * 512;
  int i = blockIdx.x * blockDim.x + threadIdx.x;
  int m = i / M, r = i - m * M;
  const float* src = (m == 0) ? a : (m == 1) ? b : (m == 2) ? c : d;
  Wb[i] = f2bf(src[r]);
}

__global__ void prep_meta(int* __restrict__ meta) {
  int i = threadIdx.x;
  if (i < 128) meta[i] = 0;            // pflags + wtflags
  else if (i < 192) meta[i] = -1;      // xcc table
}

// ---------------------------------------------------------------------------
__global__ void __launch_bounds__(NTHR, 1) bigru_rec(
    const unsigned short* __restrict__ Xb,
    unsigned short* __restrict__ Hf, unsigned short* __restrict__ Hb,
    const unsigned short* __restrict__ Wb,
    const float* __restrict__ bih_f, const float* __restrict__ bhh_f,
    const float* __restrict__ bih_b, const float* __restrict__ bhh_b,
    int* __restrict__ meta, float* __restrict__ out)
{
  const int bid  = blockIdx.x;
  const int r8   = bid & 7;
  if (r8 > 1) return;                  // non-workers exit
  const int d    = r8;                 // direction
  const int j    = bid >> 3;           // slice (16 hidden cols)
  const int tid  = threadIdx.x;
  const int w    = tid >> 6;           // 0 = gh wave, 1 = gi wave
  const int lane = tid & 63;
  const int l15  = lane & 15;
  const int hi   = lane >> 4;
  const int lk   = hi * 8;
  const int col  = j * 16 + l15;

  unsigned short* Hst = d ? Hb : Hf;
  int* pflg = meta + d * NW;           // plain flags (L2-local fast path)
  int* wflg = meta + 64 + d * NW;      // write-through flags (L3 truth)
  int* xtab = meta + 128;              // xcc table, 64 entries
  const float* bih = d ? bih_b : bih_f;
  const float* bhh = d ? bhh_b : bhh_f;

  __shared__ float fifo[RD][64][17];
  __shared__ int wrote_s, consumed_s;
  if (tid == 0) { wrote_s = 0; consumed_s = 0; }
  __syncthreads();

  // Weights: plain loads; used only via "a" MFMA constraint -> homed in AGPRs.
  const int src = w;                   // 0=Whh, 1=Wih
  int4v wf[3][16];
#pragma unroll
  for (int g = 0; g < 3; ++g) {
    const unsigned short* wrow =
        Wb + (size_t)((d * 2 + src) * 1536 + g * 512 + j * 16 + l15) * 512 + lk;
#pragma unroll
    for (int kk = 0; kk < 16; ++kk)
      wf[g][kk] = *(const int4v*)(wrow + kk * 32);
  }

  if (w == 0) {
    // ====================== WAVE A: gh + gates + publish ===================
    // XCC rendezvous (r6-proven agent atomics): decide local (XCD L2) mode.
    const int my_xcc = __builtin_amdgcn_s_getreg(20 | (0 << 6) | (31 << 11));
    if (lane == 0)
      __hip_atomic_store(xtab + d * NW + j, my_xcc, __ATOMIC_RELAXED,
                         __HIP_MEMORY_SCOPE_AGENT);
    int xv_ = -1;
    do {
      xv_ = __hip_atomic_load(xtab + lane, __ATOMIC_RELAXED,
                              __HIP_MEMORY_SCOPE_AGENT);
    } while (!__all(xv_ != -1));
    const int ref0 = __shfl(xv_, 0);          // dir-0 representative
    const int ref1 = __shfl(xv_, 32);         // dir-1 representative
    const bool grp_eq = __all(xv_ == ((lane >> 5) ? ref1 : ref0));
    const bool local_mode = grp_eq && (ref0 != ref1) &&
                            ((unsigned)ref0 < 8u) && ((unsigned)ref1 < 8u);
    bool use_local = local_mode;              // consumer path (sticky escape)

    __builtin_amdgcn_s_setprio(1);
    const float bh0 = bhh[col], bh1 = bhh[512 + col], bh2 = bhh[1024 + col];
    float hc[4] = {0.f, 0.f, 0.f, 0.f};

    for (int t = 0; t < TT; ++t) {
      f32x4 a0 = {0,0,0,0}, a1 = {0,0,0,0}, a2 = {0,0,0,0},
            a3 = {0,0,0,0}, a4 = {0,0,0,0}, a5 = {0,0,0,0};
      if (t > 0) {
        int vv = t, spins = 0;
        for (;;) {
          if (use_local) {
            if (lane < NW)
              asm volatile("global_load_dword %0, %1, off sc0\n\t"
                           "s_waitcnt vmcnt(0)"
                           : "=v"(vv) : "v"(pflg + lane) : "memory");
            if (__all(lane < NW ? (vv >= t) : 1)) break;
            if (++spins >= 512) use_local = false;   // sc0 assumption escape
          } else {
            if (lane < NW)
              vv = __hip_atomic_load(wflg + lane, __ATOMIC_RELAXED,
                                     __HIP_MEMORY_SCOPE_AGENT);
            if (__all(lane < NW ? (vv >= t) : 1)) break;
          }
        }
        __builtin_amdgcn_sched_barrier(0);   // no load hoisting above the poll
        // h loads: PLAIN in both modes (local: same-XCD L2 dirty-hit;
        // fallback: L3 truth, address cold everywhere).
        const unsigned short* Arow =
            Hst + (size_t)((t - 1) * BB + l15) * FF + lk;
        int4v af[16];
#pragma unroll
        for (int kk = 0; kk < 16; ++kk)
          af[kk] = *(const int4v*)(Arow + kk * 32);
#pragma unroll
        for (int kk = 0; kk < 16; kk += 2) {
          MFMA_AB(a0, af[kk],     wf[0][kk]);
          MFMA_AB(a2, af[kk],     wf[1][kk]);
          MFMA_AB(a4, af[kk],     wf[2][kk]);
          MFMA_AB(a1, af[kk + 1], wf[0][kk + 1]);
          MFMA_AB(a3, af[kk + 1], wf[1][kk + 1]);
          MFMA_AB(a5, af[kk + 1], wf[2][kk + 1]);
        }
        asm volatile("s_nop 7\n\ts_nop 7");  // MFMA D -> VALU hazard guard
      }
      const int slot = t & (RD - 1);
      while (__hip_atomic_load(&wrote_s, __ATOMIC_ACQUIRE,
                               __HIP_MEMORY_SCOPE_WORKGROUP) < t + 1) {}
      float fr[4], fz[4], fn[4], fx[4];
#pragma unroll
      for (int jj = 0; jj < 4; ++jj) {
        fr[jj] = fifo[slot][lane][jj];
        fz[jj] = fifo[slot][lane][4 + jj];
        fn[jj] = fifo[slot][lane][8 + jj];
        fx[jj] = fifo[slot][lane][12 + jj];
      }
      __hip_atomic_store(&consumed_s, t + 1, __ATOMIC_RELEASE,
                         __HIP_MEMORY_SCOPE_WORKGROUP);

      unsigned short us[4]; float h2v[4];
#pragma unroll
      for (int jj = 0; jj < 4; ++jj) {
        const float ghr = a0[jj] + a1[jj] + bh0;
        const float ghz = a2[jj] + a3[jj] + bh1;
        const float ghn = a4[jj] + a5[jj] + bh2;
        const float rr = 1.f / (1.f + __expf(-(fr[jj] + ghr)));
        const float zz = 1.f / (1.f + __expf(-(fz[jj] + ghz)));
        const float ee = __expf(2.f * (fn[jj] + rr * ghn));
        const float nn = 1.f - 2.f / (ee + 1.f);        // tanh, inf-safe
        const float h2 = (1.f - zz) * nn + zz * hc[jj] + fx[jj];
        hc[jj] = h2; h2v[jj] = h2; us[jj] = f2bf(h2);
      }
      // publish h: local -> plain write-back (dirty in shared XCD L2);
      // fallback -> r6 write-through agent stores.
#pragma unroll
      for (int jj = 0; jj < 4; ++jj) {
        const unsigned int other =
            (unsigned int)(unsigned short)__shfl_xor((int)us[jj], 1);
        if (!(lane & 1)) {
          const unsigned int word = (unsigned int)us[jj] | (other << 16);
          unsigned int* wp = (unsigned int*)
              (Hst + (size_t)(t * BB + hi * 4 + jj) * FF + col);
          if (local_mode) *(volatile unsigned int*)wp = word;
          else __hip_atomic_store(wp, word, __ATOMIC_RELAXED,
                                  __HIP_MEMORY_SCOPE_AGENT);
        }
      }
      asm volatile("s_waitcnt vmcnt(0)" ::: "memory");   // h at coherence point
      if (lane == 0) {
        if (local_mode) *(volatile int*)(pflg + j) = t + 1;   // L2 fast flag
        __hip_atomic_store(wflg + j, t + 1, __ATOMIC_RELAXED, // L3 truth flag
                           __HIP_MEMORY_SCOPE_AGENT);
      }
      if (t >= LL && t < TT - LL) {
#pragma unroll
        for (int jj = 0; jj < 4; ++jj)
          out[((size_t)(hi * 4 + jj) * (TT - 2 * LL) + (t - LL)) * 1024
              + d * 512 + col] = h2v[jj];
      }
    }
  } else {
    // ====================== WAVE B: gi + residual -> FIFO ==================
    const float bi0 = bih[col], bi1 = bih[512 + col], bi2 = bih[1024 + col];
    for (int t = 0; t < TT; ++t) {
      const int slot = t & (RD - 1);
      while (t - __hip_atomic_load(&consumed_s, __ATOMIC_ACQUIRE,
                                   __HIP_MEMORY_SCOPE_WORKGROUP) >= RD) {}
      const int tx = d ? (TT - 1 - t) : t;
      const unsigned short* Arow = Xb + (size_t)(tx * BB + l15) * FF + lk;
      int4v af[16];
#pragma unroll
      for (int kk = 0; kk < 16; ++kk)
        af[kk] = *(const int4v*)(Arow + kk * 32);
      f32x4 a0 = {0,0,0,0}, a1 = {0,0,0,0}, a2 = {0,0,0,0},
            a3 = {0,0,0,0}, a4 = {0,0,0,0}, a5 = {0,0,0,0};
#pragma unroll
      for (int kk = 0; kk < 16; kk += 2) {
        MFMA_AB(a0, af[kk],     wf[0][kk]);
        MFMA_AB(a2, af[kk],     wf[1][kk]);
        MFMA_AB(a4, af[kk],     wf[2][kk]);
        MFMA_AB(a1, af[kk + 1], wf[0][kk + 1]);
        MFMA_AB(a3, af[kk + 1], wf[1][kk + 1]);
        MFMA_AB(a5, af[kk + 1], wf[2][kk + 1]);
      }
      asm volatile("s_nop 7\n\ts_nop 7");
      float xv[4];
#pragma unroll
      for (int jj = 0; jj < 4; ++jj)
        xv[jj] = bf2f(Xb[(size_t)(tx * BB + hi * 4 + jj) * FF + col]);
#pragma unroll
      for (int jj = 0; jj < 4; ++jj) {
        fifo[slot][lane][jj]      = a0[jj] + a1[jj] + bi0;
        fifo[slot][lane][4 + jj]  = a2[jj] + a3[jj] + bi1;
        fifo[slot][lane][8 + jj]  = a4[jj] + a5[jj] + bi2;
        fifo[slot][lane][12 + jj] = xv[jj];
      }
      __hip_atomic_store(&wrote_s, t + 1, __ATOMIC_RELEASE,
                         __HIP_MEMORY_SCOPE_WORKGROUP);
    }
  }
}

// ---------------------------------------------------------------------------
extern "C" void kernel_launch(void* const* d_in, const int* in_sizes, int n_in,
                              void* d_out, int out_size, void* d_ws, size_t ws_size,
                              hipStream_t stream) {
  const float* x     = (const float*)d_in[0];
  const float* Wih_f = (const float*)d_in[1];
  const float* Whh_f = (const float*)d_in[2];
  const float* bih_f = (const float*)d_in[3];
  const float* bhh_f = (const float*)d_in[4];
  const float* Wih_b = (const float*)d_in[5];
  const float* Whh_b = (const float*)d_in[6];
  const float* bih_b = (const float*)d_in[7];
  const float* bhh_b = (const float*)d_in[8];
  float* out = (float*)d_out;

  char* ws = (char*)d_ws;
  unsigned short* Xb = (unsigned short*)ws;
  unsigned short* Hf = (unsigned short*)(ws + (size_t)33554432);
  unsigned short* Hb = (unsigned short*)(ws + (size_t)2 * 33554432);
  unsigned short* Wb = (unsigned short*)(ws + (size_t)3 * 33554432);
  int* meta          = (int*)(ws + (size_t)3 * 33554432 + 6291456);

  prep_x<<<65536, 256, 0, stream>>>(x, Xb);
  prep_w<<<12288, 256, 0, stream>>>(Whh_f, Wih_f, Whh_b, Wih_b, Wb);
  prep_meta<<<1, 256, 0, stream>>>(meta);
  bigru_rec<<<256, NTHR, 0, stream>>>(Xb, Hf, Hb, Wb, bih_f, bhh_f, bih_b, bhh_b,
                                      meta, out);
}

// Round 8
// 5568.702 us; speedup vs baseline: 1.6814x; 1.6814x over previous
//
#include <hip/hip_runtime.h>

// ---------------------------------------------------------------------------
// BiGRU encoder, MI355X. Round 8 = round 6 (proven, 5.94 ms) + two contention
// fixes, nothing else:
//  1) flag REPLICAS x4 per direction: consumers poll replica (j&3) -> 8
//     readers/line instead of 32; s_sleep backoff in the poll loop.
//  2) full-line h publish: shfl-transpose the block's 512B step output into
//     32 lanes x dwordx4 = 4 full 128B lines, write-through (sc0 sc1).
//
// 64 blocks, 128 threads (2 waves), 1 block/CU.
//   wave A: gh = h@Whh^T (48 MFMA, B from AGPR) + gates + publish, in-register.
//   wave B: gi = x@Wih^T + bih + residual x -> LDS FIFO (runs ahead, RD=4).
//
// ws layout:
//   Xb   [T][B][F] bf16      33,554,432 B
//   Hf   [T][B][F] bf16      33,554,432 B
//   Hb   [T][B][F] bf16      33,554,432 B
//   Wb   [2][2][1536][512]    6,291,456 B   (dir, src{0=Whh,1=Wih})
//   flags 2 dirs x 4 replicas x 32 int  (= 256 int, 4 lines per dir)
// ---------------------------------------------------------------------------

#define TT 2048
#define BB 16
#define FF 512
#define LL 10
#define RD 4
#define NTHR 128

typedef __attribute__((ext_vector_type(8))) short short8;
typedef __attribute__((ext_vector_type(4))) int   int4v;
typedef __attribute__((ext_vector_type(4))) float f32x4;

// D = A*B + C, B operand pinned to AGPR (weights live there loop-invariantly).
#define MFMA_AB(acc, a, b) \
  asm("v_mfma_f32_16x16x32_bf16 %0, %1, %2, %0" : "+v"(acc) : "v"(a), "a"(b))

__device__ __forceinline__ unsigned short f2bf(float f) {
  union { float f; unsigned int u; } v; v.f = f;
  unsigned int u = v.u;
  return (unsigned short)((u + 0x7fffu + ((u >> 16) & 1u)) >> 16);
}
__device__ __forceinline__ float bf2f(unsigned short h) {
  union { unsigned int u; float f; } v; v.u = ((unsigned int)h) << 16;
  return v.f;
}

__global__ void prep_x(const float* __restrict__ x, unsigned short* __restrict__ Xb) {
  int i = blockIdx.x * blockDim.x + threadIdx.x;
  int f = i & (FF - 1);
  int b = (i >> 9) & (BB - 1);
  int t = i >> 13;
  Xb[i] = f2bf(x[(size_t)b * (TT * 1025) + t * 1025 + f]);
}

__global__ void prep_w(const float* __restrict__ a, const float* __restrict__ b,
                       const float* __restrict__ c, const float* __restrict__ d,
                       unsigned short* __restrict__ Wb) {
  const int M = 1536 * 512;
  int i = blockIdx.x * blockDim.x + threadIdx.x;
  int m = i / M, r = i - m * M;
  const float* src = (m == 0) ? a : (m == 1) ? b : (m == 2) ? c : d;
  Wb[i] = f2bf(src[r]);
}

__global__ void prep_flags(int* __restrict__ flags) {
  int i = threadIdx.x;
  if (i < 256) flags[i] = 0;
}

// ---------------------------------------------------------------------------
__global__ void __launch_bounds__(NTHR, 1) bigru_rec(
    const unsigned short* __restrict__ Xb,
    unsigned short* __restrict__ Hf, unsigned short* __restrict__ Hb,
    const unsigned short* __restrict__ Wb,
    const float* __restrict__ bih_f, const float* __restrict__ bhh_f,
    const float* __restrict__ bih_b, const float* __restrict__ bhh_b,
    int* __restrict__ flags, float* __restrict__ out)
{
  const int bid  = blockIdx.x;
  const int d    = bid >> 5;           // direction
  const int j    = bid & 31;           // slice (16 hidden cols)
  const int tid  = threadIdx.x;
  const int w    = tid >> 6;           // 0 = gh wave, 1 = gi wave
  const int lane = tid & 63;
  const int l15  = lane & 15;
  const int hi   = lane >> 4;
  const int lk   = hi * 8;
  const int col  = j * 16 + l15;

  unsigned short* Hst = d ? Hb : Hf;
  int* flg = flags + d * 128;          // 4 replica lines of 32 ints
  const float* bih = d ? bih_b : bih_f;
  const float* bhh = d ? bhh_b : bhh_f;

  __shared__ float fifo[RD][64][17];
  __shared__ int wrote_s, consumed_s;
  if (tid == 0) { wrote_s = 0; consumed_s = 0; }
  __syncthreads();

  // Weights: plain loads; used only via "a" MFMA constraint -> homed in AGPRs.
  const int src = w;                   // 0=Whh, 1=Wih
  int4v wf[3][16];
#pragma unroll
  for (int g = 0; g < 3; ++g) {
    const unsigned short* wrow =
        Wb + (size_t)((d * 2 + src) * 1536 + g * 512 + j * 16 + l15) * 512 + lk;
#pragma unroll
    for (int kk = 0; kk < 16; ++kk)
      wf[g][kk] = *(const int4v*)(wrow + kk * 32);
  }

  if (w == 0) {
    // ====================== WAVE A: gh + gates + publish ===================
    __builtin_amdgcn_s_setprio(1);
    const float bh0 = bhh[col], bh1 = bhh[512 + col], bh2 = bhh[1024 + col];
    float hc[4] = {0.f, 0.f, 0.f, 0.f};
    int* myrep = flg + (j & 3) * 32;   // this consumer's flag replica line

    for (int t = 0; t < TT; ++t) {
      f32x4 a0 = {0,0,0,0}, a1 = {0,0,0,0}, a2 = {0,0,0,0},
            a3 = {0,0,0,0}, a4 = {0,0,0,0}, a5 = {0,0,0,0};
      if (t > 0) {
        int vv = t;
        bool first = true;
        for (;;) {
          if (lane < 32)
            vv = __hip_atomic_load(myrep + lane, __ATOMIC_RELAXED,
                                   __HIP_MEMORY_SCOPE_AGENT);
          if (__all(lane < 32 ? (vv >= t) : 1)) break;
          if (!first) asm volatile("s_sleep 1");   // backoff the poll storm
          first = false;
        }
        __builtin_amdgcn_sched_barrier(0);   // no load hoisting above the poll
        const unsigned short* Arow =
            Hst + (size_t)((t - 1) * BB + l15) * FF + lk;
        int4v af[16];
#pragma unroll
        for (int kk = 0; kk < 16; ++kk)
          af[kk] = *(const int4v*)(Arow + kk * 32);
#pragma unroll
        for (int kk = 0; kk < 16; kk += 2) {
          MFMA_AB(a0, af[kk],     wf[0][kk]);
          MFMA_AB(a2, af[kk],     wf[1][kk]);
          MFMA_AB(a4, af[kk],     wf[2][kk]);
          MFMA_AB(a1, af[kk + 1], wf[0][kk + 1]);
          MFMA_AB(a3, af[kk + 1], wf[1][kk + 1]);
          MFMA_AB(a5, af[kk + 1], wf[2][kk + 1]);
        }
        asm volatile("s_nop 7\n\ts_nop 7");  // MFMA D -> VALU hazard guard
      }
      const int slot = t & (RD - 1);
      while (__hip_atomic_load(&wrote_s, __ATOMIC_ACQUIRE,
                               __HIP_MEMORY_SCOPE_WORKGROUP) < t + 1) {}
      float fr[4], fz[4], fn[4], fx[4];
#pragma unroll
      for (int jj = 0; jj < 4; ++jj) {
        fr[jj] = fifo[slot][lane][jj];
        fz[jj] = fifo[slot][lane][4 + jj];
        fn[jj] = fifo[slot][lane][8 + jj];
        fx[jj] = fifo[slot][lane][12 + jj];
      }
      __hip_atomic_store(&consumed_s, t + 1, __ATOMIC_RELEASE,
                         __HIP_MEMORY_SCOPE_WORKGROUP);

      unsigned short us[4]; float h2v[4];
#pragma unroll
      for (int jj = 0; jj < 4; ++jj) {
        const float ghr = a0[jj] + a1[jj] + bh0;
        const float ghz = a2[jj] + a3[jj] + bh1;
        const float ghn = a4[jj] + a5[jj] + bh2;
        const float rr = 1.f / (1.f + __expf(-(fr[jj] + ghr)));
        const float zz = 1.f / (1.f + __expf(-(fz[jj] + ghz)));
        const float ee = __expf(2.f * (fn[jj] + rr * ghn));
        const float nn = 1.f - 2.f / (ee + 1.f);        // tanh, inf-safe
        const float h2 = (1.f - zz) * nn + zz * hc[jj] + fx[jj];
        hc[jj] = h2; h2v[jj] = h2; us[jj] = f2bf(h2);
      }
      // --- full-line h publish: shfl-transpose 512B into 32 lanes x 16B ---
      unsigned int word4[4];
#pragma unroll
      for (int jj = 0; jj < 4; ++jj) {
        const unsigned int other =
            (unsigned int)(unsigned short)__shfl_xor((int)us[jj], 1);
        word4[jj] = (unsigned int)us[jj] | (other << 16);  // valid in even lanes
      }
      const int s  = lane & 31;        // writer slot
      const int rs = s >> 1;           // row 0..15
      const int hs = s & 1;            // col-half (8 cols = 16B)
      int4v pk;
#pragma unroll
      for (int k = 0; k < 4; ++k) {
        const int srcl = ((rs >> 2) << 4) + hs * 8 + 2 * k;  // even lane
        unsigned int v = 0;
#pragma unroll
        for (int jj = 0; jj < 4; ++jj) {
          const unsigned int tmp = (unsigned int)__shfl((int)word4[jj], srcl);
          if ((rs & 3) == jj) v = tmp;
        }
        pk[k] = (int)v;
      }
      if (lane < 32) {
        unsigned short* wp = Hst + (size_t)(t * BB + rs) * FF + j * 16 + hs * 8;
        asm volatile("global_store_dwordx4 %0, %1, off sc0 sc1"
                     :: "v"(wp), "v"(pk) : "memory");
      }
      asm volatile("s_waitcnt vmcnt(0)" ::: "memory");   // h at coherence point
      if (lane == 0) {                 // publish to all 4 replica lines
#pragma unroll
        for (int r = 0; r < 4; ++r)
          __hip_atomic_store(flg + r * 32 + j, t + 1, __ATOMIC_RELAXED,
                             __HIP_MEMORY_SCOPE_AGENT);
      }
      if (t >= LL && t < TT - LL) {
#pragma unroll
        for (int jj = 0; jj < 4; ++jj)
          out[((size_t)(hi * 4 + jj) * (TT - 2 * LL) + (t - LL)) * 1024
              + d * 512 + col] = h2v[jj];
      }
    }
  } else {
    // ====================== WAVE B: gi + residual -> FIFO ==================
    const float bi0 = bih[col], bi1 = bih[512 + col], bi2 = bih[1024 + col];
    for (int t = 0; t < TT; ++t) {
      const int slot = t & (RD - 1);
      while (t - __hip_atomic_load(&consumed_s, __ATOMIC_ACQUIRE,
                                   __HIP_MEMORY_SCOPE_WORKGROUP) >= RD) {}
      const int tx = d ? (TT - 1 - t) : t;
      const unsigned short* Arow = Xb + (size_t)(tx * BB + l15) * FF + lk;
      int4v af[16];
#pragma unroll
      for (int kk = 0; kk < 16; ++kk)
        af[kk] = *(const int4v*)(Arow + kk * 32);
      f32x4 a0 = {0,0,0,0}, a1 = {0,0,0,0}, a2 = {0,0,0,0},
            a3 = {0,0,0,0}, a4 = {0,0,0,0}, a5 = {0,0,0,0};
#pragma unroll
      for (int kk = 0; kk < 16; kk += 2) {
        MFMA_AB(a0, af[kk],     wf[0][kk]);
        MFMA_AB(a2, af[kk],     wf[1][kk]);
        MFMA_AB(a4, af[kk],     wf[2][kk]);
        MFMA_AB(a1, af[kk + 1], wf[0][kk + 1]);
        MFMA_AB(a3, af[kk + 1], wf[1][kk + 1]);
        MFMA_AB(a5, af[kk + 1], wf[2][kk + 1]);
      }
      asm volatile("s_nop 7\n\ts_nop 7");
      float xv[4];
#pragma unroll
      for (int jj = 0; jj < 4; ++jj)
        xv[jj] = bf2f(Xb[(size_t)(tx * BB + hi * 4 + jj) * FF + col]);
#pragma unroll
      for (int jj = 0; jj < 4; ++jj) {
        fifo[slot][lane][jj]      = a0[jj] + a1[jj] + bi0;
        fifo[slot][lane][4 + jj]  = a2[jj] + a3[jj] + bi1;
        fifo[slot][lane][8 + jj]  = a4[jj] + a5[jj] + bi2;
        fifo[slot][lane][12 + jj] = xv[jj];
      }
      __hip_atomic_store(&wrote_s, t + 1, __ATOMIC_RELEASE,
                         __HIP_MEMORY_SCOPE_WORKGROUP);
    }
  }
}

// ---------------------------------------------------------------------------
extern "C" void kernel_launch(void* const* d_in, const int* in_sizes, int n_in,
                              void* d_out, int out_size, void* d_ws, size_t ws_size,
                              hipStream_t stream) {
  const float* x     = (const float*)d_in[0];
  const float* Wih_f = (const float*)d_in[1];
  const float* Whh_f = (const float*)d_in[2];
  const float* bih_f = (const float*)d_in[3];
  const float* bhh_f = (const float*)d_in[4];
  const float* Wih_b = (const float*)d_in[5];
  const float* Whh_b = (const float*)d_in[6];
  const float* bih_b = (const float*)d_in[7];
  const float* bhh_b = (const float*)d_in[8];
  float* out = (float*)d_out;

  char* ws = (char*)d_ws;
  unsigned short* Xb = (unsigned short*)ws;
  unsigned short* Hf = (unsigned short*)(ws + (size_t)33554432);
  unsigned short* Hb = (unsigned short*)(ws + (size_t)2 * 33554432);
  unsigned short* Wb = (unsigned short*)(ws + (size_t)3 * 33554432);
  int* flags         = (int*)(ws + (size_t)3 * 33554432 + 6291456);

  prep_x<<<65536, 256, 0, stream>>>(x, Xb);
  prep_w<<<12288, 256, 0, stream>>>(Whh_f, Wih_f, Whh_b, Wih_b, Wb);
  prep_flags<<<1, 256, 0, stream>>>(flags);
  bigru_rec<<<64, NTHR, 0, stream>>>(Xb, Hf, Hb, Wb, bih_f, bhh_f, bih_b, bhh_b,
                                     flags, out);
}